// Round 12
// baseline (574.765 us; speedup 1.0000x reference)
//
#include <hip/hip_runtime.h>

#define HH  64
#define WW  96
#define CC  128
#define BB  2
#define HWI (HH*WW)

#define PXB  8           // pixels per block (x)
#define TCOL 28          // staged cols [s_tile, s_tile+28)
#define ROWB (TCOL*64)   // 1792 B per staged row
#define BUFB (20*ROWB)   // 35840 B = 35 x 1KB chunks
#define NCHK 35
#define AOFF BUFB
#define ASTR 272
#define LDSZ (AOFF + 16*ASTR)   // 40192 B
#define REP  16          // internal reps: lifts each probe above the 42us fill rows

typedef __attribute__((ext_vector_type(8))) _Float16 half8;
typedef __attribute__((ext_vector_type(4))) _Float16 half4;
typedef __attribute__((ext_vector_type(4))) float    f32x4;
typedef unsigned int u32;

__device__ __forceinline__ void gll16(const void* g, void* l) {
    __builtin_amdgcn_global_load_lds(
        (const __attribute__((address_space(1))) u32*)g,
        (__attribute__((address_space(3))) u32*)l, 16, 0, 0);
}

// ---- prologue (verbatim R9) ----
__global__ __launch_bounds__(256) void conv_i2(const float* __restrict__ I2,
                                               unsigned char* __restrict__ I2t)
{
    const int idx = blockIdx.x*256 + threadIdx.x;
    const int g   = idx & 3;
    const int L   = idx >> 2;
    const int col = L % WW;
    int t = L / WW;
    const int row = t & 63;  t >>= 6;
    const int kc  = t & 3;
    const int b   = t >> 2;
    const int slot = g ^ ((col ^ (col >> 2)) & 3);

    const float* src = I2 + ((size_t)(b*CC + kc*32 + g*8)*HH + row)*WW + col;
    half8 h;
#pragma unroll
    for (int j = 0; j < 8; ++j) h[j] = (_Float16)src[(size_t)j*HWI];
    *(half8*)(I2t + (size_t)L*64 + slot*16) = h;
}

// ---- phase-ablation probe: R9 body, MODE-gated, internal x16 rep loop ----
// MODE 0: A-stage + DMA staging rounds only
// MODE 1: + bf ds_read_b128 + MFMA
// MODE 2: + D dump
// MODE 3: full (combine + stores) -- graded output, launched last
template<int MODE>
__global__ __launch_bounds__(256, 4) void corr_probe(
    const float* __restrict__ I1,
    const unsigned char* __restrict__ I2t,
    const float* __restrict__ flow,
    float* __restrict__ out)
{
    __shared__ __align__(16) unsigned char smem[LDSZ];

    const int tid  = threadIdx.x;
    const int lane = tid & 63;
    const int w    = tid >> 6;
    const int X  = blockIdx.x * PXB;
    const int y0 = blockIdx.y * 2;
    const int b  = blockIdx.z;
    const int s_tile = min(max(X - 9, 0), WW - TCOL);

    const int fpx = lane & 15;
    const int kg  = lane >> 4;
    const int cpx = tid & 7;
    const int oq  = tid >> 3;
    const int xx  = X + cpx;

#pragma unroll 1
    for (int rep = 0; rep < REP; ++rep) {
        __syncthreads();   // prev rep's combine reads done before LDS overwrite

        // ---- identity + flow loads (all modes, every rep) ----
        float cxv[2], cyv[2];
#pragma unroll
        for (int yloc = 0; yloc < 2; ++yloc) {
            const int yy = y0 + yloc;
            cxv[yloc] = (float)xx + flow[((size_t)(b*2+0)*HH + yy)*WW + xx];
            cyv[yloc] = (float)yy + flow[((size_t)(b*2+1)*HH + yy)*WW + xx];
        }

        // ---- stage A (verbatim R9) ----
#pragma unroll
        for (int i = 0; i < 2; ++i) {
            const int e   = tid + 256*i;
            const int q   = e & 1;
            const int ch  = (e >> 1) & 127;
            const int myy = e >> 8;
            const float4 v = *(const float4*)&I1[((size_t)(b*CC + ch)*HH + y0 + myy)*WW + X + q*4];
            const float ve[4] = { v.x, v.y, v.z, v.w };
#pragma unroll
            for (int k = 0; k < 4; ++k) {
                const int m = myy*8 + q*4 + k;
                *(_Float16*)(smem + AOFF + m*ASTR + ch*2) = (_Float16)ve[k];
            }
        }

        // ---- B-fragment LDS offsets (verbatim R9) ----
        int boff[9];
#pragma unroll
        for (int i = 0; i < 9; ++i) {
            const int t   = min(w + 4*i, NCHK - 1);
            const int n   = t*16 + fpx;
            const int r_t = n / TCOL;
            const int c_t = n - r_t*TCOL;
            const int col = s_tile + c_t;
            boff[i] = r_t*ROWB + c_t*64 + ((kg ^ ((col ^ (col >> 2)) & 3)) << 4);
        }
        const int aoff = AOFF + fpx*ASTR + (kg << 4);

        // ---- DMA staging (verbatim R9) ----
        auto stage = [&](int rr) {
#pragma unroll
            for (int i = 0; i < 9; ++i) {
                const int p = w + 4*i;
                if (p < NCHK) {
                    const int z   = p*1024 + lane*16;
                    const int r_t = z / ROWB;
                    const int off = z - r_t*ROWB;
                    const int c   = off >> 6;
                    const int lb  = off & 63;
                    const int grow = min(max(y0 - 9 + r_t, 0), HH - 1);
                    const unsigned char* src = I2t
                        + ((size_t)(((b*4 + rr)*HH + grow)*WW + s_tile + c))*64 + lb;
                    gll16(src, smem + p*1024);
                }
            }
        };

        f32x4 acc[9];
#pragma unroll
        for (int i = 0; i < 9; ++i) acc[i] = (f32x4){0.f,0.f,0.f,0.f};

        stage(0);
        __syncthreads();

#pragma unroll
        for (int r = 0; r < 4; ++r) {
            if constexpr (MODE >= 1) {
                const half8 af = *(const half8*)(smem + aoff + r*64);
#pragma unroll
                for (int i = 0; i < 9; ++i) {
                    if (w + 4*i < NCHK) {
                        const half8 bf = *(const half8*)(smem + boff[i]);
                        acc[i] = __builtin_amdgcn_mfma_f32_16x16x32_f16(af, bf, acc[i], 0, 0, 0);
                    }
                }
            }
            __syncthreads();
            if (r < 3) {
                stage(r + 1);
                __syncthreads();
            }
        }

        _Float16* D = (_Float16*)smem;
        if constexpr (MODE >= 2) {
#pragma unroll
            for (int i = 0; i < 9; ++i) {
                if (w + 4*i < NCHK) {
                    const int n   = (w + 4*i)*16 + fpx;
                    const int r_t = n / TCOL;
                    const int c_t = n - r_t*TCOL;
                    const half4 hv = { (_Float16)acc[i][0], (_Float16)acc[i][1],
                                       (_Float16)acc[i][2], (_Float16)acc[i][3] };
                    *(half4*)(D + (c_t*21 + r_t)*20 + kg*4) = hv;
                }
            }
        }
        __syncthreads();

        if constexpr (MODE == 3) {
            // ---- combine (verbatim R9) ----
#pragma unroll
            for (int yloc = 0; yloc < 2; ++yloc) {
                const int yy = y0 + yloc;
                const int m  = yloc*8 + cpx;
                const float cx = cxv[yloc], cy = cyv[yloc];
                const int x0c = (int)floorf(cx);
                const int y0c = (int)floorf(cy);
                const float wx1 = cx - (float)x0c, wx0 = 1.f - wx1;
                const float wy1 = cy - (float)y0c, wy0 = 1.f - wy1;
                float* outb = out + (size_t)b*81*HWI + (size_t)yy*WW + xx;

#pragma unroll
                for (int k = 0; k < 3; ++k) {
                    const int o = oq + 32*k;
                    if (o < 81) {
                        const int dyi = o / 9;
                        const int dxi = o - dyi*9;
                        const int ix0 = x0c - 4 + dxi;
                        const int iy0 = y0c - 4 + dyi;
                        const bool vx0 = (ix0   >= 0) && (ix0   < WW);
                        const bool vx1 = (ix0+1 >= 0) && (ix0+1 < WW);
                        const bool vy0 = (iy0   >= 0) && (iy0   < HH);
                        const bool vy1 = (iy0+1 >= 0) && (iy0+1 < HH);
                        const int rt  = iy0 - y0 + 9;
                        const int r0c = min(max(rt,     0), 19);
                        const int r1c = min(max(rt + 1, 0), 19);
                        const int c0  = ix0 - s_tile;
                        const int c0c = min(max(c0,     0), TCOL-1);
                        const int c1c = min(max(c0 + 1, 0), TCOL-1);
                        const float d00 = (float)D[(c0c*21 + r0c)*20 + m];
                        const float d01 = (float)D[(c1c*21 + r0c)*20 + m];
                        const float d10 = (float)D[(c0c*21 + r1c)*20 + m];
                        const float d11 = (float)D[(c1c*21 + r1c)*20 + m];
                        const float r0 = (vx0 ? wx0*d00 : 0.f) + (vx1 ? wx1*d01 : 0.f);
                        const float r1 = (vx0 ? wx0*d10 : 0.f) + (vx1 ? wx1*d11 : 0.f);
                        const float v  = (vy0 ? wy0*r0 : 0.f) + (vy1 ? wy1*r1 : 0.f);
                        outb[(size_t)o*HWI] = v;
                    }
                }
            }
        } else {
            // ---- keepalive (rule #17): runtime-never-true guarded store keeps
            //      acc / cxv / staged LDS live without DCE ----
            float kv = cxv[0] + cyv[1] + acc[0][0] + acc[8][3]
                     + (float)*(_Float16*)(smem + ((tid*2) & (BUFB - 2)));
            if (xx == 9999) out[0] = kv;   // xx <= 95: never executes
        }
    }
}

extern "C" void kernel_launch(void* const* d_in, const int* in_sizes, int n_in,
                              void* d_out, int out_size, void* d_ws, size_t ws_size,
                              hipStream_t stream)
{
    const float* I1   = (const float*)d_in[0];
    const float* I2   = (const float*)d_in[1];
    const float* flow = (const float*)d_in[2];
    float* out = (float*)d_out;
    unsigned char* I2t = (unsigned char*)d_ws;   // 3,145,728 B

    conv_i2<<<dim3(768), dim3(256), 0, stream>>>(I2, I2t);

    // ---- PHASE-ABLATION PROBE (measurement round; score sacrificial) ----
    // Per-phase cost = (dur[MODE] - dur[MODE-1]) / REP. probe<3> runs last
    // and produces the graded output (combine writes every element).
    dim3 grid(WW/PXB, HH/2, BB), blk(256);
    corr_probe<0><<<grid, blk, 0, stream>>>(I1, I2t, flow, out);
    corr_probe<1><<<grid, blk, 0, stream>>>(I1, I2t, flow, out);
    corr_probe<2><<<grid, blk, 0, stream>>>(I1, I2t, flow, out);
    corr_probe<3><<<grid, blk, 0, stream>>>(I1, I2t, flow, out);
}

// Round 13
// 20.035 us; speedup vs baseline: 28.6875x; 28.6875x over previous
//
#include <hip/hip_runtime.h>

#define HH  64
#define WW  96
#define CC  128
#define BB  2
#define HWI (HH*WW)

#define PXB  8           // pixels per block (x)
#define TCOL 28          // staged cols [s_tile, s_tile+28) ⊇ needed [X-9, X+17]
#define ROWB (TCOL*64)   // 1792 B per staged row
#define BUFB (20*ROWB)   // 35840 B = 35 x 1KB chunks exactly
#define NCHK 35          // DMA chunks / n-tiles per round
#define AOFF BUFB        // A tile after the single B buffer
#define ASTR 272         // A row stride
#define LDSZ (AOFF + 16*ASTR)   // 40192 B -> 4 blocks/CU capacity

typedef __attribute__((ext_vector_type(8))) _Float16 half8;
typedef __attribute__((ext_vector_type(4))) _Float16 half4;
typedef __attribute__((ext_vector_type(4))) float    f32x4;
typedef unsigned int u32;

__device__ __forceinline__ void gll16(const void* g, void* l) {
    __builtin_amdgcn_global_load_lds(
        (const __attribute__((address_space(1))) u32*)g,
        (__attribute__((address_space(3))) u32*)l, 16, 0, 0);   // width 16: HW-verified
}

// ---- prologue (verbatim R9): I2 fp32 -> I2t fp16 [b][kc32][row][col][4 granules x 16B]
__global__ __launch_bounds__(256) void conv_i2(const float* __restrict__ I2,
                                               unsigned char* __restrict__ I2t)
{
    const int idx = blockIdx.x*256 + threadIdx.x;   // 196608
    const int g   = idx & 3;
    const int L   = idx >> 2;                       // ((b*4+kc)*64+row)*96+col
    const int col = L % WW;
    int t = L / WW;
    const int row = t & 63;  t >>= 6;
    const int kc  = t & 3;
    const int b   = t >> 2;
    const int slot = g ^ ((col ^ (col >> 2)) & 3);

    const float* src = I2 + ((size_t)(b*CC + kc*32 + g*8)*HH + row)*WW + col;
    half8 h;
#pragma unroll
    for (int j = 0; j < 8; ++j) h[j] = (_Float16)src[(size_t)j*HWI];
    *(half8*)(I2t + (size_t)L*64 + slot*16) = h;
}

// ---- main (R9 body; ONLY change = XCD-aware block swizzle for L2 locality) ----
// XCD k (bid&7, round-robin dispatch) gets batch b = k>>2 and y-band (k&3):
// its 96 blocks share a 35-row I2t slice (~0.86 MB) that stays L2-resident,
// converting the 35x halo re-reads from HBM fetches into L2 hits.
__global__ __launch_bounds__(256, 4) void corr_kernel(
    const float* __restrict__ I1,
    const unsigned char* __restrict__ I2t,
    const float* __restrict__ flow,
    float* __restrict__ out)
{
    __shared__ __align__(16) unsigned char smem[LDSZ];

    const int tid  = threadIdx.x;
    const int lane = tid & 63;
    const int w    = tid >> 6;      // 4 waves

    // ---- XCD swizzle (bijective on 0..767) ----
    const int bid = blockIdx.x;     // flat 0..767
    const int xcd = bid & 7;
    const int j   = bid >> 3;       // 0..95
    const int b   = xcd >> 2;                            // 0..1
    const int y0  = 16*(xcd & 3) + 2*(j & 7);            // 0..62, even
    const int X   = (j >> 3) * PXB;                      // 0..88

    const int s_tile = min(max(X - 9, 0), WW - TCOL);

    const int fpx = lane & 15;      // MFMA n-lane / m-lane
    const int kg  = lane >> 4;      // k-group

    // ---- hoisted combine identity + flow loads ----
    const int cpx = tid & 7;
    const int oq  = tid >> 3;       // 0..31
    const int xx  = X + cpx;
    float cxv[2], cyv[2];
#pragma unroll
    for (int yloc = 0; yloc < 2; ++yloc) {
        const int yy = y0 + yloc;
        cxv[yloc] = (float)xx + flow[((size_t)(b*2+0)*HH + yy)*WW + xx];
        cyv[yloc] = (float)yy + flow[((size_t)(b*2+1)*HH + yy)*WW + xx];
    }

    // ---- stage A: fp16 [m16][ch128] stride 272B, float4 I1 loads (verbatim R9) ----
#pragma unroll
    for (int i = 0; i < 2; ++i) {
        const int e   = tid + 256*i;        // 0..511
        const int q   = e & 1;
        const int ch  = (e >> 1) & 127;
        const int myy = e >> 8;
        const float4 v = *(const float4*)&I1[((size_t)(b*CC + ch)*HH + y0 + myy)*WW + X + q*4];
        const float ve[4] = { v.x, v.y, v.z, v.w };
#pragma unroll
        for (int k = 0; k < 4; ++k) {
            const int m = myy*8 + q*4 + k;
            *(_Float16*)(smem + AOFF + m*ASTR + ch*2) = (_Float16)ve[k];
        }
    }

    // ---- hoisted B-fragment offsets: n = r_t*28 + c_t over 35 tiles (verbatim R9) ----
    int boff[9];
#pragma unroll
    for (int i = 0; i < 9; ++i) {
        const int t   = min(w + 4*i, NCHK - 1);
        const int n   = t*16 + fpx;
        const int r_t = n / TCOL;
        const int c_t = n - r_t*TCOL;
        const int col = s_tile + c_t;
        boff[i] = r_t*ROWB + c_t*64 + ((kg ^ ((col ^ (col >> 2)) & 3)) << 4);
    }
    const int aoff = AOFF + fpx*ASTR + (kg << 4);

    // ---- async staging: round rr (32 ch) -> single buffer; 35 x 1KB DMA chunks ----
    auto stage = [&](int rr) {
#pragma unroll
        for (int i = 0; i < 9; ++i) {
            const int p = w + 4*i;              // wave-uniform
            if (p < NCHK) {
                const int z   = p*1024 + lane*16;
                const int r_t = z / ROWB;           // staged row 0..19
                const int off = z - r_t*ROWB;
                const int c   = off >> 6;
                const int lb  = off & 63;
                const int grow = min(max(y0 - 9 + r_t, 0), HH - 1);
                const unsigned char* src = I2t
                    + ((size_t)(((b*4 + rr)*HH + grow)*WW + s_tile + c))*64 + lb;
                gll16(src, smem + p*1024);
            }
        }
    };

    f32x4 acc[9];
#pragma unroll
    for (int i = 0; i < 9; ++i) acc[i] = (f32x4){0.f,0.f,0.f,0.f};

    stage(0);
    __syncthreads();                 // A visible + DMA(0) drained

#pragma unroll
    for (int r = 0; r < 4; ++r) {
        const half8 af = *(const half8*)(smem + aoff + r*64);
#pragma unroll
        for (int i = 0; i < 9; ++i) {
            if (w + 4*i < NCHK) {               // wave-uniform predicate
                const half8 bf = *(const half8*)(smem + boff[i]);
                acc[i] = __builtin_amdgcn_mfma_f32_16x16x32_f16(af, bf, acc[i], 0, 0, 0);
            }
        }
        __syncthreads();             // all reads of buffer done
        if (r < 3) {
            stage(r + 1);            // overwrite buffer
            __syncthreads();         // DMA(r+1) drained for everyone
        }
    }

    // ---- dump D fp16 [c28][r pad21][m pad20] via ds_write_b64 (verbatim R9) ----
    _Float16* D = (_Float16*)smem;
#pragma unroll
    for (int i = 0; i < 9; ++i) {
        if (w + 4*i < NCHK) {
            const int n   = (w + 4*i)*16 + fpx;
            const int r_t = n / TCOL;
            const int c_t = n - r_t*TCOL;
            const half4 hv = { (_Float16)acc[i][0], (_Float16)acc[i][1],
                               (_Float16)acc[i][2], (_Float16)acc[i][3] };
            *(half4*)(D + (c_t*21 + r_t)*20 + kg*4) = hv;   // m = kg*4..kg*4+3
        }
    }
    __syncthreads();

    // ---- combine: 81 outputs x (8px, 2rows), shared bilinear weights (verbatim R9) ----
#pragma unroll
    for (int yloc = 0; yloc < 2; ++yloc) {
        const int yy = y0 + yloc;
        const int m  = yloc*8 + cpx;
        const float cx = cxv[yloc], cy = cyv[yloc];
        const int x0c = (int)floorf(cx);
        const int y0c = (int)floorf(cy);
        const float wx1 = cx - (float)x0c, wx0 = 1.f - wx1;
        const float wy1 = cy - (float)y0c, wy0 = 1.f - wy1;
        float* outb = out + (size_t)b*81*HWI + (size_t)yy*WW + xx;

#pragma unroll
        for (int k = 0; k < 3; ++k) {
            const int o = oq + 32*k;
            if (o < 81) {
                const int dyi = o / 9;
                const int dxi = o - dyi*9;
                const int ix0 = x0c - 4 + dxi;
                const int iy0 = y0c - 4 + dyi;
                const bool vx0 = (ix0   >= 0) && (ix0   < WW);
                const bool vx1 = (ix0+1 >= 0) && (ix0+1 < WW);
                const bool vy0 = (iy0   >= 0) && (iy0   < HH);
                const bool vy1 = (iy0+1 >= 0) && (iy0+1 < HH);
                const int rt  = iy0 - y0 + 9;
                const int r0c = min(max(rt,     0), 19);
                const int r1c = min(max(rt + 1, 0), 19);
                const int c0  = ix0 - s_tile;
                const int c0c = min(max(c0,     0), TCOL-1);
                const int c1c = min(max(c0 + 1, 0), TCOL-1);
                const float d00 = (float)D[(c0c*21 + r0c)*20 + m];
                const float d01 = (float)D[(c1c*21 + r0c)*20 + m];
                const float d10 = (float)D[(c0c*21 + r1c)*20 + m];
                const float d11 = (float)D[(c1c*21 + r1c)*20 + m];
                const float r0 = (vx0 ? wx0*d00 : 0.f) + (vx1 ? wx1*d01 : 0.f);
                const float r1 = (vx0 ? wx0*d10 : 0.f) + (vx1 ? wx1*d11 : 0.f);
                const float v  = (vy0 ? wy0*r0 : 0.f) + (vy1 ? wy1*r1 : 0.f);
                outb[(size_t)o*HWI] = v;
            }
        }
    }
}

extern "C" void kernel_launch(void* const* d_in, const int* in_sizes, int n_in,
                              void* d_out, int out_size, void* d_ws, size_t ws_size,
                              hipStream_t stream)
{
    const float* I1   = (const float*)d_in[0];
    const float* I2   = (const float*)d_in[1];
    const float* flow = (const float*)d_in[2];
    float* out = (float*)d_out;
    unsigned char* I2t = (unsigned char*)d_ws;   // 3,145,728 B

    conv_i2<<<dim3(768), dim3(256), 0, stream>>>(I2, I2t);
    corr_kernel<<<dim3(768), dim3(256), 0, stream>>>(I1, I2t, flow, out);
}